// Round 2
// baseline (648.304 us; speedup 1.0000x reference)
//
#include <hip/hip_runtime.h>
#include <hip/hip_bf16.h>
#include <cstdint>

#define NN 2048
#define BB 8
#define DIN 128
#define DOUT 64
#define LRELU_ALPHA 0.2f
#define TM 32     // output rows per attn block
#define TN 256    // n-tile per phase

// ---------------------------------------------------------------------------
// Kernel 1: xp = x @ W^T + b ; e_src[r] = xp[r].a_src ; e_dst[r] = xp[r].a_dst
// 16 rows per block, 256 threads. Thread (lane=d, w) holds W[d][w*32..w*32+31]
// in 32 registers (loaded as float4 from the L1-resident 32 KB W); x rows are
// broadcast from LDS. Cross-wave (k-split) reduce via LDS.
// ---------------------------------------------------------------------------
__global__ __launch_bounds__(256) void gat_xp_kernel(
    const float* __restrict__ x, const float* __restrict__ W,
    const float* __restrict__ bias, const float* __restrict__ a,
    float* __restrict__ xp, float* __restrict__ e_src, float* __restrict__ e_dst)
{
    __shared__ float xl[16 * DIN];        // 8 KB
    __shared__ float red[4 * 16 * 64];    // 16 KB  [w][r*64+d]

    const int t = threadIdx.x;
    const int lane = t & 63;              // output dim d
    const int w = t >> 6;                 // k-split: k in [w*32, w*32+32)
    const int R0 = blockIdx.x * 16;

    // Stage 16 x rows (coalesced).
    #pragma unroll
    for (int i = 0; i < 8; ++i)
        xl[i * 256 + t] = x[(size_t)R0 * DIN + i * 256 + t];

    // W fragment into registers: W[lane][w*32 + j], 8 x float4 (16B aligned).
    float wreg[32];
    const float4* wp = (const float4*)(W + lane * DIN + w * 32);
    #pragma unroll
    for (int j = 0; j < 8; ++j) {
        const float4 v = wp[j];
        wreg[j * 4 + 0] = v.x; wreg[j * 4 + 1] = v.y;
        wreg[j * 4 + 2] = v.z; wreg[j * 4 + 3] = v.w;
    }
    __syncthreads();

    // Partial dot products over this wave's k-range for all 16 rows.
    float part[16];
    #pragma unroll
    for (int r = 0; r < 16; ++r) {
        const float* xr = &xl[r * DIN + w * 32];   // broadcast reads
        float p = 0.f;
        #pragma unroll
        for (int j = 0; j < 32; ++j) p += wreg[j] * xr[j];
        part[r] = p;
    }
    #pragma unroll
    for (int r = 0; r < 16; ++r)
        red[w * 1024 + r * 64 + lane] = part[r];   // consecutive lanes: no conflict
    __syncthreads();

    // Combine k-splits. Per i, wave w owns full row r = i*4+w (d = lane).
    const float bv = bias[lane];
    const float as = a[lane];
    const float ad = a[DOUT + lane];
    #pragma unroll
    for (int i = 0; i < 4; ++i) {
        const int r = i * 4 + w;
        const float v = red[0 * 1024 + r * 64 + lane] + red[1 * 1024 + r * 64 + lane]
                      + red[2 * 1024 + r * 64 + lane] + red[3 * 1024 + r * 64 + lane] + bv;
        xp[(size_t)(R0 + r) * DOUT + lane] = v;
        float es = v * as;
        float ed = v * ad;
        #pragma unroll
        for (int off = 32; off >= 1; off >>= 1) {
            es += __shfl_xor(es, off);
            ed += __shfl_xor(ed, off);
        }
        if (lane == 0) {
            e_src[R0 + r] = es;
            e_dst[R0 + r] = ed;
        }
    }
}

// ---------------------------------------------------------------------------
// Kernel 2: one block per (batch, 32-row m-tile). 256 threads = 4 waves.
// Softmax shift = leaky(s_m + dmax_batch) >= true masked row max (leaky is
// monotone), so no per-row max pass is needed; ratios after normalization are
// mathematically identical to the reference.
// Per n-tile of 256: phase A computes p (coalesced adj stream) into LDS,
// phase B accumulates PV with acc[32] in registers (p broadcast as float4,
// xp coalesced 256B/wave from L2).
// ---------------------------------------------------------------------------
__global__ __launch_bounds__(256) void gat_attn_kernel(
    const int* __restrict__ adj, const float* __restrict__ xp,
    const float* __restrict__ e_src, const float* __restrict__ e_dst,
    float* __restrict__ out)
{
    __shared__ float d_lds[NN];          // 8 KB: e_dst for the batch
    __shared__ float p_lds[TM * TN];     // 32 KB: p tile; reused for reductions
    __shared__ float s_lds[TM];
    __shared__ float bnd_lds[TM];
    __shared__ float inv_lds[TM];
    __shared__ float redmax[4];

    const int t = threadIdx.x;
    const int lane = t & 63;
    const int w = t >> 6;
    const int bpb = NN / TM;                       // 64 blocks per batch
    const int b = blockIdx.x / bpb;
    const int m0 = (blockIdx.x % bpb) * TM;
    const size_t base = (size_t)b * NN;

    // Stage e_dst for the batch; fold in the per-batch max reduce.
    float dm = -1e30f;
    #pragma unroll
    for (int i = 0; i < 8; ++i) {
        const float v = e_dst[base + i * 256 + t];
        d_lds[i * 256 + t] = v;
        dm = fmaxf(dm, v);
    }
    #pragma unroll
    for (int off = 32; off >= 1; off >>= 1)
        dm = fmaxf(dm, __shfl_xor(dm, off));
    if (lane == 0) redmax[w] = dm;
    __syncthreads();
    const float dmax = fmaxf(fmaxf(redmax[0], redmax[1]), fmaxf(redmax[2], redmax[3]));

    if (t < TM) {
        const float s = e_src[base + m0 + t];
        s_lds[t] = s;
        const float e = s + dmax;
        bnd_lds[t] = (e > 0.f) ? e : LRELU_ALPHA * e;   // upper bound of row max
    }
    __syncthreads();

    float acc[TM];
    float rs[TM];
    #pragma unroll
    for (int r = 0; r < TM; ++r) { acc[r] = 0.f; rs[r] = 0.f; }

    for (int t0 = 0; t0 < NN; t0 += TN) {
        // ---- phase A: probabilities for the 32 x 256 tile ----
        const float dn = d_lds[t0 + t];
        #pragma unroll
        for (int r = 0; r < TM; ++r) {
            const int av = adj[(size_t)(base + m0 + r) * NN + t0 + t];  // coalesced
            float e = s_lds[r] + dn;
            e = (e > 0.f) ? e : LRELU_ALPHA * e;
            const float p = av ? __expf(e - bnd_lds[r]) : 0.f;
            rs[r] += p;
            p_lds[r * TN + t] = p;
        }
        __syncthreads();

        // ---- phase B: PV accumulate ----
        const float* __restrict__ xpt = xp + (base + t0) * DOUT + lane;
        #pragma unroll
        for (int i = 0; i < TN / 16; ++i) {
            const int n0 = i * 16 + w * 4;
            float xv0 = xpt[(size_t)(n0 + 0) * DOUT];
            float xv1 = xpt[(size_t)(n0 + 1) * DOUT];
            float xv2 = xpt[(size_t)(n0 + 2) * DOUT];
            float xv3 = xpt[(size_t)(n0 + 3) * DOUT];
            #pragma unroll
            for (int r = 0; r < TM; ++r) {
                const float4 p4 = *(const float4*)&p_lds[r * TN + n0];  // broadcast
                acc[r] += p4.x * xv0 + p4.y * xv1 + p4.z * xv2 + p4.w * xv3;
            }
        }
        __syncthreads();   // before phase A overwrites p_lds
    }

    // ---- row-sum reduce (reuse p_lds) ----
    #pragma unroll
    for (int r = 0; r < TM; ++r) p_lds[r * 256 + t] = rs[r];
    __syncthreads();
    #pragma unroll
    for (int k = 0; k < 8; ++k) {
        const int r = w * 8 + k;
        float v = p_lds[r * 256 + lane] + p_lds[r * 256 + 64 + lane]
                + p_lds[r * 256 + 128 + lane] + p_lds[r * 256 + 192 + lane];
        #pragma unroll
        for (int off = 32; off >= 1; off >>= 1) v += __shfl_xor(v, off);
        if (lane == 0) inv_lds[r] = 1.f / v;
    }
    __syncthreads();

    // ---- cross-wave PV reduce (reuse p_lds: [w][r*64+d] = 4*2048 floats) ----
    #pragma unroll
    for (int r = 0; r < TM; ++r) p_lds[w * 2048 + r * 64 + lane] = acc[r];
    __syncthreads();
    #pragma unroll
    for (int i = 0; i < 8; ++i) {
        const int r = i * 4 + w;
        const float v = (p_lds[0 * 2048 + r * 64 + lane] + p_lds[1 * 2048 + r * 64 + lane]
                       + p_lds[2 * 2048 + r * 64 + lane] + p_lds[3 * 2048 + r * 64 + lane])
                      * inv_lds[r];
        out[(size_t)(base + m0 + r) * DOUT + lane] = v;   // coalesced
    }
}

extern "C" void kernel_launch(void* const* d_in, const int* in_sizes, int n_in,
                              void* d_out, int out_size, void* d_ws, size_t ws_size,
                              hipStream_t stream) {
    const float* x    = (const float*)d_in[0];
    const int*   adj  = (const int*)d_in[1];
    const float* W    = (const float*)d_in[2];
    const float* bvec = (const float*)d_in[3];
    const float* a    = (const float*)d_in[4];
    float* out = (float*)d_out;

    float* xp    = (float*)d_ws;                       // B*N*64 f32
    float* e_src = xp + (size_t)BB * NN * DOUT;        // B*N
    float* e_dst = e_src + (size_t)BB * NN;            // B*N

    gat_xp_kernel<<<(BB * NN) / 16, 256, 0, stream>>>(x, W, bvec, a, xp, e_src, e_dst);
    gat_attn_kernel<<<BB * (NN / TM), 256, 0, stream>>>(adj, xp, e_src, e_dst, out);
}

// Round 3
// 226.325 us; speedup vs baseline: 2.8645x; 2.8645x over previous
//
#include <hip/hip_runtime.h>
#include <hip/hip_bf16.h>
#include <cstdint>

#define NN 2048
#define BB 8
#define DIN 128
#define DOUT 64

typedef __attribute__((ext_vector_type(8))) short bf16x8;
typedef __attribute__((ext_vector_type(4))) float f32x4;

static __device__ __forceinline__ short f2b(float f) {
    union { __hip_bfloat16 h; short s; } u;
    u.h = __float2bfloat16(f);
    return u.s;
}

// ---------------------------------------------------------------------------
// Kernel 1: xp = x@W^T + b via MFMA bf16 (f32 loads, in-register cvt).
// Writes xpT[b][d][n] (bf16, d-major for PV B-frags) and e_src/e_dst (fp32
// from the fp32 accumulators). Block = 256 thr = 4 waves x 16 rows; no LDS.
// A-frag: lane holds x[r0+(l&15)][ks*32+(l>>4)*8 + 0..7]  (16B contiguous)
// B-frag: lane holds W[dt*16+(l&15)][ks*32+(l>>4)*8 + 0..7]
// C-frag (m89-verified): col = l&15, row = (l>>4)*4 + reg.
// ---------------------------------------------------------------------------
__global__ __launch_bounds__(256) void gat_xp_mfma(
    const float* __restrict__ x, const float* __restrict__ W,
    const float* __restrict__ bias, const float* __restrict__ a,
    unsigned short* __restrict__ xpT, float* __restrict__ e_src,
    float* __restrict__ e_dst)
{
    const int t = threadIdx.x;
    const int lane = t & 63;
    const int w = t >> 6;
    const int lr = lane & 15;
    const int g  = lane >> 4;
    const int r0 = blockIdx.x * 64 + w * 16;   // wave's 16-row tile

    f32x4 acc[4] = {};
    const float* xrow = x + (size_t)(r0 + lr) * DIN + g * 8;
    #pragma unroll
    for (int ks = 0; ks < 4; ++ks) {
        const float4 xa = *(const float4*)(xrow + ks * 32);
        const float4 xb = *(const float4*)(xrow + ks * 32 + 4);
        bf16x8 afr;
        afr[0] = f2b(xa.x); afr[1] = f2b(xa.y); afr[2] = f2b(xa.z); afr[3] = f2b(xa.w);
        afr[4] = f2b(xb.x); afr[5] = f2b(xb.y); afr[6] = f2b(xb.z); afr[7] = f2b(xb.w);
        #pragma unroll
        for (int dt = 0; dt < 4; ++dt) {
            const float* wrow = W + (size_t)(dt * 16 + lr) * DIN + ks * 32 + g * 8;
            const float4 wa = *(const float4*)(wrow);
            const float4 wb = *(const float4*)(wrow + 4);
            bf16x8 bfr;
            bfr[0] = f2b(wa.x); bfr[1] = f2b(wa.y); bfr[2] = f2b(wa.z); bfr[3] = f2b(wa.w);
            bfr[4] = f2b(wb.x); bfr[5] = f2b(wb.y); bfr[6] = f2b(wb.z); bfr[7] = f2b(wb.w);
            acc[dt] = __builtin_amdgcn_mfma_f32_16x16x32_bf16(afr, bfr, acc[dt], 0, 0, 0);
        }
    }

    // Epilogue: bias add, xpT store, rank-1 logit dots from fp32 accumulators.
    const int b  = r0 >> 11;           // uniform per block (2048 % 64 == 0)
    const int nb = r0 & (NN - 1);
    float es[4] = {0.f, 0.f, 0.f, 0.f};
    float ed[4] = {0.f, 0.f, 0.f, 0.f};
    #pragma unroll
    for (int dt = 0; dt < 4; ++dt) {
        const int d = dt * 16 + lr;
        const float bv  = bias[d];
        const float asv = a[d];
        const float adv = a[DOUT + d];
        #pragma unroll
        for (int reg = 0; reg < 4; ++reg) {
            const float v = acc[dt][reg] + bv;
            const int n = nb + g * 4 + reg;
            xpT[((size_t)(b * DOUT + d) << 11) + n] = (unsigned short)f2b(v);
            es[reg] += v * asv;
            ed[reg] += v * adv;
        }
    }
    #pragma unroll
    for (int reg = 0; reg < 4; ++reg) {
        #pragma unroll
        for (int off = 1; off < 16; off <<= 1) {
            es[reg] += __shfl_xor(es[reg], off);
            ed[reg] += __shfl_xor(ed[reg], off);
        }
    }
    if (lr == 0) {
        #pragma unroll
        for (int reg = 0; reg < 4; ++reg) {
            e_src[r0 + g * 4 + reg] = es[reg];
            e_dst[r0 + g * 4 + reg] = ed[reg];
        }
    }
}

// Kernel 2: per-batch max of e_dst (softmax shift bound input).
__global__ __launch_bounds__(256) void gat_dmax(
    const float* __restrict__ e_dst, float* __restrict__ dmax)
{
    __shared__ float red[4];
    const int b = blockIdx.x, t = threadIdx.x;
    float m = -1e30f;
    #pragma unroll
    for (int i = 0; i < 8; ++i)
        m = fmaxf(m, e_dst[(size_t)b * NN + i * 256 + t]);
    #pragma unroll
    for (int off = 32; off >= 1; off >>= 1)
        m = fmaxf(m, __shfl_xor(m, off));
    if ((t & 63) == 0) red[t >> 6] = m;
    __syncthreads();
    if (t == 0) dmax[b] = fmaxf(fmaxf(red[0], red[1]), fmaxf(red[2], red[3]));
}

// ---------------------------------------------------------------------------
// Kernel 3: fused masked-softmax + PV via MFMA.
// Block = 4 waves, all on the SAME 16 output rows; waves n-split (512 each).
// P generated directly in the A-frag layout: lane (l) owns row l&15, and
// n = n0 + (l>>4)*8 + j. Shift = leaky(s_m + dmax_b) >= row max (monotone),
// softmax-invariant. B-frag = 16B contiguous load from xpT[d][n].
// Cross-wave combine of C-frags + rowsums via LDS, then normalize.
// ---------------------------------------------------------------------------
__global__ __launch_bounds__(256) void gat_attn_mfma(
    const int* __restrict__ adj, const unsigned short* __restrict__ xpT,
    const float* __restrict__ e_src, const float* __restrict__ e_dst,
    const float* __restrict__ dmax, float* __restrict__ out)
{
    __shared__ float d_lds[NN];            // 8 KB e_dst batch
    __shared__ float o_lds[4 * 16 * 65];   // 16.6 KB padded C combine
    __shared__ float rs_lds[4 * 16];

    const int t = threadIdx.x;
    const int lane = t & 63;
    const int w = t >> 6;
    const int lr = lane & 15;
    const int g  = lane >> 4;
    const int b  = blockIdx.x >> 7;            // 128 row-tiles per batch
    const int m0 = (blockIdx.x & 127) * 16;
    const size_t base = (size_t)b * NN;

    #pragma unroll
    for (int i = 0; i < 8; ++i)
        d_lds[i * 256 + t] = e_dst[base + i * 256 + t];
    __syncthreads();

    const float s_r = e_src[base + m0 + lr];      // row l&15 (A-frag row)
    const float e0  = s_r + dmax[b];
    const float bnd = fmaxf(e0, 0.2f * e0);       // leaky, upper bound of row max

    const int n_base = w * 512;
    const int* __restrict__ adjrow = adj + ((base + m0 + lr) << 11);
    const unsigned short* __restrict__ xb = xpT + ((size_t)(b * DOUT) << 11);

    f32x4 acc[4] = {};
    float rs = 0.f;

    for (int ks = 0; ks < 16; ++ks) {
        const int n0 = n_base + ks * 32 + g * 8;
        const int4   a0 = *(const int4*)(adjrow + n0);
        const int4   a1 = *(const int4*)(adjrow + n0 + 4);
        const float4 d0 = *(const float4*)(d_lds + n0);
        const float4 d1 = *(const float4*)(d_lds + n0 + 4);
        const float dv[8] = {d0.x, d0.y, d0.z, d0.w, d1.x, d1.y, d1.z, d1.w};
        const int   av[8] = {a0.x, a0.y, a0.z, a0.w, a1.x, a1.y, a1.z, a1.w};
        float pv[8];
        #pragma unroll
        for (int j = 0; j < 8; ++j) {
            const float e = s_r + dv[j];
            const float le = fmaxf(e, 0.2f * e);
            const float pe = __expf(le - bnd);
            pv[j] = av[j] ? pe : 0.f;
            rs += pv[j];
        }
        bf16x8 afr;
        #pragma unroll
        for (int j = 0; j < 8; ++j) afr[j] = f2b(pv[j]);
        #pragma unroll
        for (int dt = 0; dt < 4; ++dt) {
            const bf16x8 bfr = *(const bf16x8*)(xb + ((size_t)(dt * 16 + lr) << 11) + n0);
            acc[dt] = __builtin_amdgcn_mfma_f32_16x16x32_bf16(afr, bfr, acc[dt], 0, 0, 0);
        }
    }

    // row-sums: reduce across k-groups (lanes differing in bits 4,5)
    rs += __shfl_xor(rs, 16);
    rs += __shfl_xor(rs, 32);
    if (lane < 16) rs_lds[w * 16 + lane] = rs;

    // C-frags to LDS (row = (l>>4)*4+reg, col = dt*16 + (l&15))
    #pragma unroll
    for (int dt = 0; dt < 4; ++dt)
        #pragma unroll
        for (int reg = 0; reg < 4; ++reg)
            o_lds[w * 1040 + (g * 4 + reg) * 65 + dt * 16 + lr] = acc[dt][reg];
    __syncthreads();

    // combine 4 waves, normalize, write
    #pragma unroll
    for (int i = 0; i < 4; ++i) {
        const int idx = i * 256 + t;
        const int row = idx >> 6;
        const int d   = idx & 63;
        const float v = o_lds[row * 65 + d] + o_lds[1040 + row * 65 + d]
                      + o_lds[2080 + row * 65 + d] + o_lds[3120 + row * 65 + d];
        const float rst = rs_lds[row] + rs_lds[16 + row]
                        + rs_lds[32 + row] + rs_lds[48 + row];
        out[(base + m0 + row) * DOUT + d] = v / rst;
    }
}

extern "C" void kernel_launch(void* const* d_in, const int* in_sizes, int n_in,
                              void* d_out, int out_size, void* d_ws, size_t ws_size,
                              hipStream_t stream) {
    const float* x    = (const float*)d_in[0];
    const int*   adj  = (const int*)d_in[1];
    const float* W    = (const float*)d_in[2];
    const float* bvec = (const float*)d_in[3];
    const float* a    = (const float*)d_in[4];
    float* out = (float*)d_out;

    unsigned short* xpT = (unsigned short*)d_ws;              // 2 MB bf16 [b][d][n]
    float* e_src = (float*)((char*)d_ws + (1 << 21));         // 64 KB
    float* e_dst = e_src + (size_t)BB * NN;                   // 64 KB
    float* dmax  = e_dst + (size_t)BB * NN;                   // 32 B

    gat_xp_mfma<<<256, 256, 0, stream>>>(x, W, bvec, a, xpT, e_src, e_dst);
    gat_dmax<<<BB, 256, 0, stream>>>(e_dst, dmax);
    gat_attn_mfma<<<BB * 128, 256, 0, stream>>>(adj, xpT, e_src, e_dst, dmax, out);
}

// Round 4
// 214.687 us; speedup vs baseline: 3.0198x; 1.0542x over previous
//
#include <hip/hip_runtime.h>
#include <hip/hip_bf16.h>
#include <cstdint>

#define NN 2048
#define BB 8
#define DIN 128
#define DOUT 64
#define PHN 256            // n per phase in attn
#define NPH (NN / PHN)     // 8 phases
#define PCH 130            // shorts per P chunk-block: 16 rows * 8 + 2 pad

typedef __attribute__((ext_vector_type(8))) short bf16x8;
typedef __attribute__((ext_vector_type(4))) float f32x4;

static __device__ __forceinline__ unsigned short f2b(float f) {
    union { __hip_bfloat16 h; unsigned short s; } u;
    u.h = __float2bfloat16(f);
    return u.s;
}

// ---------------------------------------------------------------------------
// Kernel 1: xp = x@W^T + b via MFMA, K split across the 4 waves.
// grid = 1024 blocks x 256 thr; block owns 16 rows. Wave w covers k in
// [w*32, w*32+32): one A-frag (x), 4 B-frags (W), 4 MFMA. Partials reduced
// through padded LDS ([4][16][65] f32). Epilogue thread (row=t>>4, dq=t&15)
// sums 4 waves + bias for 4 consecutive d, emits bf16 xpT[b][d][n] and the
// rank-1 logit dots e_src/e_dst (shfl reduce over the 16 dq lanes).
// ---------------------------------------------------------------------------
__global__ __launch_bounds__(256) void gat_xp_mfma(
    const float* __restrict__ x, const float* __restrict__ W,
    const float* __restrict__ bias, const float* __restrict__ a,
    unsigned short* __restrict__ xpT, float* __restrict__ e_src,
    float* __restrict__ e_dst)
{
    __shared__ float red[4 * 16 * 65];   // 16.6 KB
    const int t = threadIdx.x;
    const int lane = t & 63;
    const int w = t >> 6;
    const int lr = lane & 15;
    const int g  = lane >> 4;
    const int r0 = blockIdx.x * 16;
    const int k0 = w * 32 + g * 8;

    const float* xr = x + (size_t)(r0 + lr) * DIN + k0;
    const float4 xa = *(const float4*)xr;
    const float4 xb4 = *(const float4*)(xr + 4);
    bf16x8 afr;
    afr[0]=f2b(xa.x);  afr[1]=f2b(xa.y);  afr[2]=f2b(xa.z);  afr[3]=f2b(xa.w);
    afr[4]=f2b(xb4.x); afr[5]=f2b(xb4.y); afr[6]=f2b(xb4.z); afr[7]=f2b(xb4.w);

    #pragma unroll
    for (int dt = 0; dt < 4; ++dt) {
        const float* wr = W + (size_t)(dt * 16 + lr) * DIN + k0;
        const float4 wa = *(const float4*)wr;
        const float4 wb = *(const float4*)(wr + 4);
        bf16x8 bfr;
        bfr[0]=f2b(wa.x); bfr[1]=f2b(wa.y); bfr[2]=f2b(wa.z); bfr[3]=f2b(wa.w);
        bfr[4]=f2b(wb.x); bfr[5]=f2b(wb.y); bfr[6]=f2b(wb.z); bfr[7]=f2b(wb.w);
        f32x4 acc = {0.f, 0.f, 0.f, 0.f};
        acc = __builtin_amdgcn_mfma_f32_16x16x32_bf16(afr, bfr, acc, 0, 0, 0);
        #pragma unroll
        for (int reg = 0; reg < 4; ++reg)
            red[w * 1040 + (g * 4 + reg) * 65 + dt * 16 + lr] = acc[reg];
    }
    __syncthreads();

    const int row = t >> 4;
    const int dq  = t & 15;
    const int b   = r0 >> 11;
    const int nb  = r0 & (NN - 1);
    float es = 0.f, ed = 0.f;
    #pragma unroll
    for (int j = 0; j < 4; ++j) {
        const int d = dq * 4 + j;
        const float v = red[0 * 1040 + row * 65 + d] + red[1 * 1040 + row * 65 + d]
                      + red[2 * 1040 + row * 65 + d] + red[3 * 1040 + row * 65 + d]
                      + bias[d];
        es += v * a[d];
        ed += v * a[DOUT + d];
        xpT[((size_t)(b * DOUT + d) << 11) + nb + row] = f2b(v);
    }
    es += __shfl_xor(es, 1); es += __shfl_xor(es, 2);
    es += __shfl_xor(es, 4); es += __shfl_xor(es, 8);
    ed += __shfl_xor(ed, 1); ed += __shfl_xor(ed, 2);
    ed += __shfl_xor(ed, 4); ed += __shfl_xor(ed, 8);
    if (dq == 0) {
        e_src[r0 + row] = es;
        e_dst[r0 + row] = ed;
    }
}

// ---------------------------------------------------------------------------
// Kernel 2: fused masked-softmax + PV. Block = 16 m-rows x full n; 4 waves
// split the 64 output cols (wave = dt). Per phase (256 n):
//   p-gen: thread (row = it*4+w, cols = lane*4) loads adj COALESCED from
//          global (prefetched one phase ahead into regs), computes
//          p = exp(leaky(s+d) - bnd) (bnd = leaky(s_m + dmax_b) >= row max,
//          softmax-invariant), packs bf16 pairs into the chunk-block P LDS
//          layout; accumulates row-sums in regs.
//   barrier (its lgkmcnt(0) drain makes one barrier/phase race-free w/ dbuf)
//   MFMA: 8 k-steps; A-frag = 4x ds_read_b32 at bank (c+4*lr+j)%32 ->
//          conflict-free; B-frag = 16B global from L2-hot xpT.
// Epilogue: shfl row-sum reduce, normalize, direct coalesced C store.
// ---------------------------------------------------------------------------
__global__ __launch_bounds__(256) void gat_attn_mfma(
    const int* __restrict__ adj, const unsigned short* __restrict__ xpT,
    const float* __restrict__ e_src, const float* __restrict__ e_dst,
    float* __restrict__ out)
{
    __shared__ float d_lds[NN];                     // 8 KB
    __shared__ unsigned short p_lds[2][32 * PCH];   // 16.6 KB
    __shared__ float mred[4];
    __shared__ float s_lds[16];
    __shared__ float bnd_lds[16];
    __shared__ float rs_lds[16];

    const int t = threadIdx.x;
    const int lane = t & 63;
    const int w = t >> 6;
    const int lr = lane & 15;
    const int g  = lane >> 4;
    const int b  = blockIdx.x >> 7;
    const int m0 = (blockIdx.x & 127) * 16;
    const size_t base = (size_t)b * NN;

    // stage e_dst for the batch + fold in the batch max (softmax shift input)
    float dm = -1e30f;
    #pragma unroll
    for (int i = 0; i < 8; ++i) {
        const float v = e_dst[base + i * 256 + t];
        d_lds[i * 256 + t] = v;
        dm = fmaxf(dm, v);
    }
    #pragma unroll
    for (int off = 32; off >= 1; off >>= 1) dm = fmaxf(dm, __shfl_xor(dm, off));
    if (lane == 0) mred[w] = dm;
    __syncthreads();
    const float dmax = fmaxf(fmaxf(mred[0], mred[1]), fmaxf(mred[2], mred[3]));
    if (t < 16) {
        const float s = e_src[base + m0 + t];
        const float e0 = s + dmax;
        s_lds[t] = s;
        bnd_lds[t] = fmaxf(e0, 0.2f * e0);
    }
    __syncthreads();

    // per-thread p-gen constants: 4 rows (it*4 + w), cols lane*4 per phase
    float srow[4], brow[4];
    const int* aptr[4];
    #pragma unroll
    for (int it = 0; it < 4; ++it) {
        const int row = it * 4 + w;
        srow[it] = s_lds[row];
        brow[it] = bnd_lds[row];
        aptr[it] = adj + ((base + (size_t)(m0 + row)) << 11) + lane * 4;
    }

    int4 acur[4], anxt[4];
    #pragma unroll
    for (int it = 0; it < 4; ++it) acur[it] = *(const int4*)(aptr[it]);

    f32x4 acc = {0.f, 0.f, 0.f, 0.f};
    float rs_acc[4] = {0.f, 0.f, 0.f, 0.f};
    const unsigned short* xb = xpT + ((size_t)(b * DOUT + w * 16 + lr) << 11);

    const int c  = lane >> 1;        // P chunk of this thread's 4 cols
    const int jj = (lane & 1) * 4;   // element offset within chunk

    int buf = 0;
    for (int ph = 0; ph < NPH; ++ph) {
        if (ph + 1 < NPH) {
            #pragma unroll
            for (int it = 0; it < 4; ++it)
                anxt[it] = *(const int4*)(aptr[it] + (ph + 1) * PHN);
        }
        // ---- p-gen ----
        const float4 dv = *(const float4*)(d_lds + ph * PHN + lane * 4);
        const float dvv[4] = {dv.x, dv.y, dv.z, dv.w};
        unsigned short* pb = &p_lds[buf][0];
        #pragma unroll
        for (int it = 0; it < 4; ++it) {
            const int row = it * 4 + w;
            const float s = srow[it], bd = brow[it];
            const int av[4] = {acur[it].x, acur[it].y, acur[it].z, acur[it].w};
            float p[4];
            #pragma unroll
            for (int j = 0; j < 4; ++j) {
                const float e = s + dvv[j];
                const float le = fmaxf(e, 0.2f * e);
                const float pe = __expf(le - bd);
                p[j] = av[j] ? pe : 0.f;
            }
            rs_acc[it] += p[0] + p[1] + p[2] + p[3];
            unsigned int* pp32 =
                (unsigned int*)(pb + c * PCH + row * 8 + jj);
            pp32[0] = ((unsigned)f2b(p[1]) << 16) | f2b(p[0]);
            pp32[1] = ((unsigned)f2b(p[3]) << 16) | f2b(p[2]);
        }
        __syncthreads();
        // ---- MFMA: 8 k-steps of 32 ----
        const unsigned int* pw = (const unsigned int*)pb;
        const int nb0 = ph * PHN;
        #pragma unroll
        for (int ks = 0; ks < 8; ++ks) {
            const int cc = ks * 4 + g;
            const int wbase = cc * 65 + lr * 4;
            union { unsigned int u[4]; bf16x8 v; } af;
            af.u[0] = pw[wbase + 0];
            af.u[1] = pw[wbase + 1];
            af.u[2] = pw[wbase + 2];
            af.u[3] = pw[wbase + 3];
            const bf16x8 bfr = *(const bf16x8*)(xb + nb0 + ks * 32 + g * 8);
            acc = __builtin_amdgcn_mfma_f32_16x16x32_bf16(af.v, bfr, acc, 0, 0, 0);
        }
        #pragma unroll
        for (int it = 0; it < 4; ++it) acur[it] = anxt[it];
        buf ^= 1;
    }

    // ---- row sums (reduce across the 64 lanes of each wave) ----
    #pragma unroll
    for (int it = 0; it < 4; ++it) {
        float v = rs_acc[it];
        #pragma unroll
        for (int off = 32; off >= 1; off >>= 1) v += __shfl_xor(v, off);
        if (lane == 0) rs_lds[it * 4 + w] = v;
    }
    __syncthreads();

    // ---- normalize + store: wave w owns cols [w*16, w*16+16) ----
    #pragma unroll
    for (int reg = 0; reg < 4; ++reg) {
        const int row = g * 4 + reg;
        const float o = acc[reg] / rs_lds[row];
        out[(base + (size_t)(m0 + row)) * DOUT + w * 16 + lr] = o;
    }
}

extern "C" void kernel_launch(void* const* d_in, const int* in_sizes, int n_in,
                              void* d_out, int out_size, void* d_ws, size_t ws_size,
                              hipStream_t stream) {
    const float* x    = (const float*)d_in[0];
    const int*   adj  = (const int*)d_in[1];
    const float* W    = (const float*)d_in[2];
    const float* bvec = (const float*)d_in[3];
    const float* a    = (const float*)d_in[4];
    float* out = (float*)d_out;

    unsigned short* xpT = (unsigned short*)d_ws;          // 2 MB bf16 [b][d][n]
    float* e_src = (float*)((char*)d_ws + (1 << 21));     // 64 KB
    float* e_dst = e_src + (size_t)BB * NN;               // 64 KB

    gat_xp_mfma<<<(BB * NN) / 16, 256, 0, stream>>>(x, W, bvec, a, xpT, e_src, e_dst);
    gat_attn_mfma<<<BB * (NN / 16), 256, 0, stream>>>(adj, xpT, e_src, e_dst, out);
}